// Round 6
// baseline (167.271 us; speedup 1.0000x reference)
//
#include <hip/hip_runtime.h>
#include <math.h>

// Problem constants (B=1)
#define TT   512
#define CEMB 768
#define NH   12
#define NKV  6
#define HD   64
#define KVC  (NKV*HD)   // 384
#define NTOT 1536       // q(768) | k(384) | v(384)
#define GP_STRIDE ((size_t)TT*NTOT)

// ---- fp32 GEMM partial: 64x64 tile, BK=16, 256 threads, 4x4 microtile ----
// Split-K: accumulates A[m0:m0+64, kbeg:kbeg+klen] @ B into per-split partials.
__device__ __forceinline__ void gemm_sk(const float* __restrict__ A,
                                        const float* __restrict__ B,
                                        float* __restrict__ P,
                                        int lda, int ldb, int ldc,
                                        int m0, int bcol, int pcol,
                                        int kbeg, int klen){
  __shared__ float As[2][16][68];
  __shared__ float Bs[2][16][68];
  int tid  = threadIdx.x;
  int arow = tid >> 2, ak4 = (tid & 3) * 4;
  int brow = tid >> 4, bc  = (tid & 15) * 4;
  int ty   = tid >> 4, tx = tid & 15;

  float acc[4][4];
  #pragma unroll
  for(int i=0;i<4;i++)
    #pragma unroll
    for(int j=0;j<4;j++) acc[i][j] = 0.f;

  const float* Ap = A + (size_t)(m0+arow)*lda + kbeg + ak4;
  const float* Bq = B + (size_t)(kbeg+brow)*ldb + bcol + bc;

  float4 a = *(const float4*)(Ap);
  float4 b = *(const float4*)(Bq);

  int buf = 0;
  for(int k0=0; k0<klen; k0+=16){
    As[buf][ak4+0][arow]=a.x; As[buf][ak4+1][arow]=a.y;
    As[buf][ak4+2][arow]=a.z; As[buf][ak4+3][arow]=a.w;
    *(float4*)&Bs[buf][brow][bc] = b;
    if (k0 + 16 < klen){
      a = *(const float4*)(Ap + k0 + 16);
      b = *(const float4*)(Bq + (size_t)(k0+16)*ldb);
    }
    __syncthreads();
    #pragma unroll
    for(int kk=0;kk<16;kk++){
      float4 av = *(float4*)&As[buf][kk][ty*4];
      float4 bv = *(float4*)&Bs[buf][kk][tx*4];
      #pragma unroll
      for(int r=0;r<4;r++)
        #pragma unroll
        for(int c=0;c<4;c++)
          acc[r][c] = fmaf((&av.x)[r], (&bv.x)[c], acc[r][c]);
    }
    buf ^= 1;
  }
  #pragma unroll
  for(int r=0;r<4;r++)
    *(float4*)(P + (size_t)(m0+ty*4+r)*ldc + pcol + tx*4) =
      make_float4(acc[r][0],acc[r][1],acc[r][2],acc[r][3]);
}

// K1: QKV split-K partials. Also zeroes the fixup counters for K2/K3.
__global__ void __launch_bounds__(256) gemm_qkv_partial(const float* __restrict__ X,
    const float* __restrict__ Wq, const float* __restrict__ Wk, const float* __restrict__ Wv,
    float* __restrict__ P, unsigned* __restrict__ cnt){
  if (blockIdx.x==0 && blockIdx.y==0 && blockIdx.z==0 && threadIdx.x < 192)
    cnt[threadIdx.x] = 0;
  int mt = blockIdx.x;   // 0..7
  int nt = blockIdx.y;   // 0..23
  int ks = blockIdx.z;   // 0..3
  const float* B; int ldb, bcol;
  if (nt < 12)      { B = Wq; ldb = CEMB; bcol = nt*64; }
  else if (nt < 18) { B = Wk; ldb = KVC;  bcol = (nt-12)*64; }
  else              { B = Wv; ldb = KVC;  bcol = (nt-18)*64; }
  gemm_sk(X, B, P + (size_t)ks*GP_STRIDE, CEMB, ldb, NTOT,
          mt*64, bcol, nt*64, ks*192, 192);
}

// merge 4 qkv split-K partials for one float4
__device__ __forceinline__ float4 load_merged(const float* __restrict__ P, int t, int col){
  size_t base = (size_t)t*NTOT + col;
  float4 a = *(const float4*)(P + base);
  float4 b = *(const float4*)(P + base + GP_STRIDE);
  float4 c = *(const float4*)(P + base + 2*GP_STRIDE);
  float4 d = *(const float4*)(P + base + 3*GP_STRIDE);
  return make_float4(a.x+b.x+c.x+d.x, a.y+b.y+c.y+d.y,
                     a.z+b.z+c.z+d.z, a.w+b.w+c.w+d.w);
}

// RoPE + RMSNorm over a 16-lane group holding one head-row (lane lc has d=lc*4..+3).
__device__ __forceinline__ float4 rope_rms4(float4 sum, int t, int lc,
    const float* __restrict__ cosb, const float* __restrict__ sinb){
  float4 prt;
  prt.x = __shfl_xor(sum.x, 8); prt.y = __shfl_xor(sum.y, 8);
  prt.z = __shfl_xor(sum.z, 8); prt.w = __shfl_xor(sum.w, 8);
  float4 cs = *(const float4*)(cosb + t*32 + (lc&7)*4);
  float4 sn = *(const float4*)(sinb + t*32 + (lc&7)*4);
  float4 rot;
  if (lc < 8){
    rot.x = sum.x*cs.x - prt.x*sn.x; rot.y = sum.y*cs.y - prt.y*sn.y;
    rot.z = sum.z*cs.z - prt.z*sn.z; rot.w = sum.w*cs.w - prt.w*sn.w;
  } else {
    rot.x = sum.x*cs.x + prt.x*sn.x; rot.y = sum.y*cs.y + prt.y*sn.y;
    rot.z = sum.z*cs.z + prt.z*sn.z; rot.w = sum.w*cs.w + prt.w*sn.w;
  }
  float ss = rot.x*rot.x + rot.y*rot.y + rot.z*rot.z + rot.w*rot.w;
  ss += __shfl_xor(ss,1); ss += __shfl_xor(ss,2);
  ss += __shfl_xor(ss,4); ss += __shfl_xor(ss,8);
  float sc = rsqrtf(ss*(1.0f/64.0f) + 1e-6f);
  rot.x*=sc; rot.y*=sc; rot.z*=sc; rot.w*=sc;
  return rot;
}

// K2: fused attention. Merges qkv partials + RoPE/RMS inline during staging,
// computes split-KV tropical attention partials, last block per (h,qt) merges
// chunks and writes ybuf (fixup via agent-scope atomic counter).
__global__ void __launch_bounds__(256) attn_fused(const float* __restrict__ P,
    const float* __restrict__ cosb, const float* __restrict__ sinb,
    float* __restrict__ part_acc, float2* __restrict__ part_ml,
    unsigned* __restrict__ cnt, float* __restrict__ ybuf){
  __shared__ float Qsh[64*64];
  __shared__ float Ksh[64*64];
  __shared__ float Vsh[64*64];
  __shared__ float Psh[64*64];
  __shared__ int lastflag;

  int h   = blockIdx.y;
  int idx = blockIdx.x;        // 0..19 -> (qt, ct); counts per qt: 1,1,2,2,3,3,4,4
  int qt, ct;
  if      (idx < 1) { qt=0; ct=idx;    }
  else if (idx < 2) { qt=1; ct=idx-1;  }
  else if (idx < 4) { qt=2; ct=idx-2;  }
  else if (idx < 6) { qt=3; ct=idx-4;  }
  else if (idx < 9) { qt=4; ct=idx-6;  }
  else if (idx < 12){ qt=5; ct=idx-9;  }
  else if (idx < 16){ qt=6; ct=idx-12; }
  else              { qt=7; ct=idx-16; }

  int kvh  = h >> 1;
  int w    = threadIdx.x >> 6;
  int lane = threadIdx.x & 63;
  int lg   = lane >> 4;
  int lc   = lane & 15;

  // stage Q: merge partials + rope + rms (wave-private rows)
  #pragma unroll
  for(int sub=0; sub<4; ++sub){
    int rr = w*16 + sub*4 + lg;
    int t  = qt*64 + rr;
    float4 qv = rope_rms4(load_merged(P, t, h*HD + lc*4), t, lc, cosb, sinb);
    *(float4*)&Qsh[rr*64 + lc*4] = qv;
  }

  float m_run[4], l_run[4], acc[4][4];
  #pragma unroll
  for(int r=0;r<4;r++){
    m_run[r] = -INFINITY; l_run[r] = 0.f;
    #pragma unroll
    for(int c=0;c<4;c++) acc[r][c] = 0.f;
  }

  int ntiles = (2*ct < qt) ? 2 : 1;

  for(int tt=0; tt<ntiles; ++tt){
    int t0 = ct*128 + tt*64;
    __syncthreads();
    #pragma unroll
    for(int sub=0; sub<4; ++sub){
      int rr = w*16 + sub*4 + lg;
      int t  = t0 + rr;
      int sw = ((lc ^ (rr>>2)) & 15)*4;
      float4 kv = rope_rms4(load_merged(P, t, 768 + kvh*HD + lc*4), t, lc, cosb, sinb);
      float4 vv = load_merged(P, t, 1152 + kvh*HD + lc*4);
      *(float4*)&Ksh[rr*64 + sw] = kv;
      *(float4*)&Vsh[rr*64 + sw] = vv;
    }
    __syncthreads();

    float s[4][4];
    #pragma unroll
    for(int r=0;r<4;r++)
      #pragma unroll
      for(int c=0;c<4;c++) s[r][c] = -INFINITY;

    #pragma unroll
    for(int dg=0; dg<16; ++dg){
      float4 k4[4], q4[4];
      int ksw = ((dg ^ lc)&15)*4;
      #pragma unroll
      for(int c=0;c<4;c++)
        k4[c] = *(const float4*)&Ksh[(lc*4+c)*64 + ksw];
      #pragma unroll
      for(int r=0;r<4;r++)
        q4[r] = *(const float4*)&Qsh[(w*16+lg*4+r)*64 + dg*4];
      #pragma unroll
      for(int r=0;r<4;r++)
        #pragma unroll
        for(int c=0;c<4;c++)
          s[r][c] = fmaxf(s[r][c],
                    fmaxf(fmaxf(q4[r].x + k4[c].x, q4[r].y + k4[c].y),
                          fmaxf(q4[r].z + k4[c].z, q4[r].w + k4[c].w)));
    }

    #pragma unroll
    for(int r=0;r<4;r++){
      int i = qt*64 + w*16 + lg*4 + r;
      #pragma unroll
      for(int c=0;c<4;c++)
        if (t0 + lc*4 + c > i) s[r][c] = -INFINITY;
      float mt = fmaxf(fmaxf(s[r][0],s[r][1]), fmaxf(s[r][2],s[r][3]));
      mt = fmaxf(mt, __shfl_xor(mt,1));
      mt = fmaxf(mt, __shfl_xor(mt,2));
      mt = fmaxf(mt, __shfl_xor(mt,4));
      mt = fmaxf(mt, __shfl_xor(mt,8));
      float m_new = fmaxf(m_run[r], mt);
      float mb    = (m_new == -INFINITY) ? 0.f : m_new;
      float corr  = __expf(m_run[r] - mb);
      float p0 = __expf(s[r][0]-mb), p1 = __expf(s[r][1]-mb);
      float p2 = __expf(s[r][2]-mb), p3 = __expf(s[r][3]-mb);
      float ps = p0+p1+p2+p3;
      ps += __shfl_xor(ps,1); ps += __shfl_xor(ps,2);
      ps += __shfl_xor(ps,4); ps += __shfl_xor(ps,8);
      l_run[r] = l_run[r]*corr + ps;
      #pragma unroll
      for(int c=0;c<4;c++) acc[r][c] *= corr;
      m_run[r] = m_new;
      *(float4*)&Psh[(w*16+lg*4+r)*64 + lc*4] = make_float4(p0,p1,p2,p3);
    }
    __builtin_amdgcn_wave_barrier();

    #pragma unroll
    for(int jg=0; jg<16; ++jg){
      float4 v4[4];
      int vsw = ((lc ^ jg)&15)*4;
      #pragma unroll
      for(int jj=0;jj<4;jj++)
        v4[jj] = *(const float4*)&Vsh[(jg*4+jj)*64 + vsw];
      #pragma unroll
      for(int r=0;r<4;r++){
        float4 p4 = *(const float4*)&Psh[(w*16+lg*4+r)*64 + jg*4];
        #pragma unroll
        for(int c=0;c<4;c++)
          acc[r][c] = fmaf(p4.x, (&v4[0].x)[c], fmaf(p4.y, (&v4[1].x)[c],
                      fmaf(p4.z, (&v4[2].x)[c], fmaf(p4.w, (&v4[3].x)[c], acc[r][c]))));
      }
    }
    __builtin_amdgcn_wave_barrier();
  }

  // write chunk partials
  #pragma unroll
  for(int r=0;r<4;r++){
    int i = qt*64 + w*16 + lg*4 + r;
    int pidx = (h*TT + i)*4 + ct;
    *(float4*)&part_acc[(size_t)pidx*64 + lc*4] =
      make_float4(acc[r][0],acc[r][1],acc[r][2],acc[r][3]);
    if (lc == 0) part_ml[pidx] = make_float2(m_run[r], l_run[r]);
  }

  // fixup: last block per (h,qt) merges chunks -> ybuf
  __syncthreads();
  if (threadIdx.x == 0){
    __builtin_amdgcn_fence(__ATOMIC_RELEASE, "agent");
    unsigned old = __hip_atomic_fetch_add(&cnt[h*8+qt], 1u,
                      __ATOMIC_RELAXED, __HIP_MEMORY_SCOPE_AGENT);
    lastflag = (old == (unsigned)(qt/2));   // nct-1
  }
  __syncthreads();
  if (lastflag){
    __builtin_amdgcn_fence(__ATOMIC_ACQUIRE, "agent");
    int g = threadIdx.x >> 4, lc2 = threadIdx.x & 15;
    int nch = qt/2 + 1;
    #pragma unroll
    for(int rrr=0; rrr<4; ++rrr){
      int i = qt*64 + g*4 + rrr;
      float m = -INFINITY, l = 0.f;
      float ax=0.f, ay=0.f, az=0.f, aw=0.f;
      for(int c=0;c<nch;c++){
        int pidx = (h*TT + i)*4 + c;
        float2 ml = part_ml[pidx];
        float4 ac = *(const float4*)&part_acc[(size_t)pidx*64 + lc2*4];
        float mn = fmaxf(m, ml.x);
        float sa = __expf(m - mn);
        float sc = __expf(ml.x - mn);
        l  = l*sa  + ml.y*sc;
        ax = ax*sa + ac.x*sc; ay = ay*sa + ac.y*sc;
        az = az*sa + ac.z*sc; aw = aw*sa + ac.w*sc;
        m = mn;
      }
      float inv = 1.0f / l;
      *(float4*)&ybuf[(size_t)i*CEMB + h*HD + lc2*4] =
        make_float4(ax*inv, ay*inv, az*inv, aw*inv);
    }
  }
}

// K3: proj split-K + fixup merge -> out
__global__ void __launch_bounds__(256) gemm_proj_fixup(const float* __restrict__ Y,
    const float* __restrict__ Wp, float* __restrict__ P,
    unsigned* __restrict__ cnt, float* __restrict__ out){
  gemm_sk(Y, Wp, P + (size_t)blockIdx.z*TT*CEMB, CEMB, CEMB, CEMB,
          blockIdx.x*64, blockIdx.y*64, blockIdx.y*64, blockIdx.z*192, 192);
  __shared__ int lastflag;
  __syncthreads();
  if (threadIdx.x == 0){
    __builtin_amdgcn_fence(__ATOMIC_RELEASE, "agent");
    unsigned old = __hip_atomic_fetch_add(&cnt[96 + blockIdx.y*8 + blockIdx.x], 1u,
                      __ATOMIC_RELAXED, __HIP_MEMORY_SCOPE_AGENT);
    lastflag = (old == 3u);
  }
  __syncthreads();
  if (lastflag){
    __builtin_amdgcn_fence(__ATOMIC_ACQUIRE, "agent");
    int ty = threadIdx.x >> 4, tx = threadIdx.x & 15;
    int m0 = blockIdx.x*64, n0 = blockIdx.y*64;
    #pragma unroll
    for(int r=0;r<4;r++){
      size_t off = (size_t)(m0+ty*4+r)*CEMB + n0 + tx*4;
      float4 a = *(const float4*)(P + off);
      float4 b = *(const float4*)(P + off + (size_t)TT*CEMB);
      float4 c = *(const float4*)(P + off + (size_t)2*TT*CEMB);
      float4 d = *(const float4*)(P + off + (size_t)3*TT*CEMB);
      *(float4*)(out + off) = make_float4(a.x+b.x+c.x+d.x, a.y+b.y+c.y+d.y,
                                          a.z+b.z+c.z+d.z, a.w+b.w+c.w+d.w);
    }
  }
}

extern "C" void kernel_launch(void* const* d_in, const int* in_sizes, int n_in,
                              void* d_out, int out_size, void* d_ws, size_t ws_size,
                              hipStream_t stream){
  const float* x    = (const float*)d_in[0];
  const float* cosb = (const float*)d_in[1];
  const float* sinb = (const float*)d_in[2];
  const float* Wq   = (const float*)d_in[3];
  const float* Wk   = (const float*)d_in[4];
  const float* Wv   = (const float*)d_in[5];
  const float* Wp   = (const float*)d_in[6];
  float* out = (float*)d_out;

  float* ws        = (float*)d_ws;
  float* gpart     = ws;                               // 4*512*1536 (qkv partials; reused for proj)
  float* ybuf      = gpart + 4*GP_STRIDE;              // 512*768
  float* part_acc  = ybuf + (size_t)TT*CEMB;           // 12*512*4*64
  float2* part_ml  = (float2*)(part_acc + (size_t)NH*TT*4*64);  // 12*512*4
  unsigned* cnt    = (unsigned*)(part_ml + NH*TT*4);   // 192 counters

  gemm_qkv_partial<<<dim3(8,24,4), 256, 0, stream>>>(x, Wq, Wk, Wv, gpart, cnt);
  attn_fused      <<<dim3(20,NH),  256, 0, stream>>>(gpart, cosb, sinb,
                                                     part_acc, part_ml, cnt, ybuf);
  gemm_proj_fixup <<<dim3(8,12,4), 256, 0, stream>>>(ybuf, Wp, gpart, cnt, out);
}